// Round 2
// baseline (498.307 us; speedup 1.0000x reference)
//
#include <hip/hip_runtime.h>
#include <hip/hip_bf16.h>
#include <math.h>

// Problem constants
#define BB 4096
#define DD 2048
#define HH 2048

typedef __bf16 bf16x8 __attribute__((ext_vector_type(8)));
typedef float f32x4 __attribute__((ext_vector_type(4)));

__device__ __forceinline__ void async16(const void* g, void* l) {
  __builtin_amdgcn_global_load_lds(
      (const __attribute__((address_space(1))) unsigned int*)g,
      (__attribute__((address_space(3))) unsigned int*)l,
      16, 0, 0);
}

__device__ __forceinline__ float sigmoidf_(float x) {
  return 1.0f / (1.0f + __expf(-x));
}

__device__ __forceinline__ void store_bf8(__hip_bfloat16* dst, const float* v) {
  union { __hip_bfloat16 b[8]; uint4 u; } p;
#pragma unroll
  for (int e = 0; e < 8; e++) p.b[e] = __float2bfloat16(v[e]);
  *(uint4*)dst = p.u;
}

// ---------------------------------------------------------------------------
// bias[g][c] = b_g[c] + rb_g[c],  g in {z,i,f,o}
__global__ void prep_bias(const float* __restrict__ bz, const float* __restrict__ bi,
                          const float* __restrict__ bf, const float* __restrict__ bo,
                          const float* __restrict__ rbz, const float* __restrict__ rbi,
                          const float* __restrict__ rbf, const float* __restrict__ rbo,
                          float* __restrict__ bias) {
  int i = blockIdx.x * 256 + threadIdx.x;
  if (i < 2048) {
    bias[0 * 2048 + i] = bz[i] + rbz[i];
    bias[1 * 2048 + i] = bi[i] + rbi[i];
    bias[2 * 2048 + i] = bf[i] + rbf[i];
    bias[3 * 2048 + i] = bo[i] + rbo[i];
  }
}

// ---------------------------------------------------------------------------
// WT[((g*4+n)*512 + j)*1024 + kt], kt<512 -> W_g[n][kt][j], kt>=512 -> R_g[n][kt-512][j]
__global__ void prep_w(const float* __restrict__ Wz, const float* __restrict__ Wi,
                       const float* __restrict__ Wf, const float* __restrict__ Wo,
                       const float* __restrict__ Rz, const float* __restrict__ Ri,
                       const float* __restrict__ Rf, const float* __restrict__ Ro,
                       __hip_bfloat16* __restrict__ WT) {
  int jt = blockIdx.x;         // 16 tiles of 32 over j
  int ktt = blockIdx.y;        // 32 tiles of 32 over kt
  int gn = blockIdx.z;         // g*4 + n
  int g = gn >> 2, nn = gn & 3;
  int ktg0 = ktt * 32;
  const float* src;
  if (ktg0 < 512) src = (g == 0 ? Wz : g == 1 ? Wi : g == 2 ? Wf : Wo);
  else            src = (g == 0 ? Rz : g == 1 ? Ri : g == 2 ? Rf : Ro);
  int ks0 = ktg0 & 511;
  int j0 = jt * 32;
  __shared__ float tile[32][33];
  int tx = threadIdx.x, ty = threadIdx.y;  // 32 x 8
#pragma unroll
  for (int r = 0; r < 4; r++) {
    int kk = ty + r * 8;
    tile[kk][tx] = src[((size_t)nn * 512 + ks0 + kk) * 512 + j0 + tx];
  }
  __syncthreads();
#pragma unroll
  for (int r = 0; r < 4; r++) {
    int jj = ty + r * 8;
    WT[((size_t)gn * 512 + j0 + jj) * 1024 + ktg0 + tx] = __float2bfloat16(tile[tx][jj]);
  }
}

// ---------------------------------------------------------------------------
// Per row: LayerNorm -> causal conv3 -> SiLU; emit bf16 x, x_conv, h_prev.
__global__ __launch_bounds__(256) void prep_act(
    const float* __restrict__ x, const float* __restrict__ h,
    const float* __restrict__ lg, const float* __restrict__ lb,
    const float* __restrict__ cw, const float* __restrict__ cb,
    __hip_bfloat16* __restrict__ xb, __hip_bfloat16* __restrict__ xcb,
    __hip_bfloat16* __restrict__ hb) {
  int row = blockIdx.x;
  int t = threadIdx.x;
  __shared__ float xn[2048];
  __shared__ float red[8];
  const float* xr = x + (size_t)row * 2048;
  const float* hr = h + (size_t)row * 2048;
  float4 v0 = ((const float4*)xr)[t * 2];
  float4 v1 = ((const float4*)xr)[t * 2 + 1];
  float vv[8] = {v0.x, v0.y, v0.z, v0.w, v1.x, v1.y, v1.z, v1.w};
  float s = 0.f, s2 = 0.f;
#pragma unroll
  for (int e = 0; e < 8; e++) { s += vv[e]; s2 += vv[e] * vv[e]; }
#pragma unroll
  for (int off = 32; off > 0; off >>= 1) {
    s += __shfl_down(s, off);
    s2 += __shfl_down(s2, off);
  }
  int w = t >> 6, l = t & 63;
  if (l == 0) { red[w] = s; red[4 + w] = s2; }
  __syncthreads();
  float mu = (red[0] + red[1] + red[2] + red[3]) * (1.0f / 2048.0f);
  float var = (red[4] + red[5] + red[6] + red[7]) * (1.0f / 2048.0f) - mu * mu;
  float rs = rsqrtf(var + 1e-5f);

  float4 h0 = ((const float4*)hr)[t * 2];
  float4 h1 = ((const float4*)hr)[t * 2 + 1];
  float hh[8] = {h0.x, h0.y, h0.z, h0.w, h1.x, h1.y, h1.z, h1.w};
  int j0 = t * 8;
#pragma unroll
  for (int e = 0; e < 8; e++) {
    int j = j0 + e;
    xn[j] = (vv[e] - mu) * rs * lg[j] + lb[j];
  }
  store_bf8(xb + (size_t)row * 2048 + j0, vv);
  store_bf8(hb + (size_t)row * 2048 + j0, hh);
  __syncthreads();
  float w0 = cw[0], w1 = cw[1], w2 = cw[2], bbv = cb[0];
  float sc[8];
#pragma unroll
  for (int e = 0; e < 8; e++) {
    int j = j0 + e;
    float a0 = (j >= 2) ? xn[j - 2] : 0.f;
    float a1 = (j >= 1) ? xn[j - 1] : 0.f;
    float xc = w0 * a0 + w1 * a1 + w2 * xn[j] + bbv;
    sc[e] = xc * sigmoidf_(xc);
  }
  store_bf8(xcb + (size_t)row * 2048 + j0, sc);
}

// ---------------------------------------------------------------------------
// Fused 4-gate block GEMM, 16x16x32 MFMA, gate-pair wave specialization.
// Grid: (4096/128, 512/64, 4). Block: 256 threads = 4 waves.
// Wave w: pair p=w>>1 (0:(z,o) A=x/h, 1:(i,f) A=xc/h), mhalf = w&1.
// Wave tile: 64m x 64j x 2 gates; S_m=4, S_j=4 subtiles of 16x16.
// Per k32 iter: 12 ds_read_b128 feed 32 MFMA -> LDS-bound util ~40%.
// Epilogue: (z,o) waves apply bias+act, write bf16 z,o to LDS; (i,f) waves
// combine with c_prev -> h,c. Exchange buffer unioned with staging LDS.
__global__ __launch_bounds__(256) void gemm_fused(
    const __hip_bfloat16* __restrict__ xb, const __hip_bfloat16* __restrict__ xcb,
    const __hip_bfloat16* __restrict__ hb, const __hip_bfloat16* __restrict__ WT,
    const float* __restrict__ bias, const float* __restrict__ c_prev,
    float* __restrict__ out) {
  // LDS: staging 32KB (As1 8K | As2 8K | Bs 16K) unioned with
  // zo exchange buffer: bf16 [2][128][68] = 34816 B.
  __shared__ __attribute__((aligned(16))) char smem[34816];
  __hip_bfloat16* As1 = (__hip_bfloat16*)smem;               // [128][32]
  __hip_bfloat16* As2 = (__hip_bfloat16*)(smem + 8192);      // [128][32]
  __hip_bfloat16* Bs  = (__hip_bfloat16*)(smem + 16384);     // [4][64][32]
  __hip_bfloat16* zo  = (__hip_bfloat16*)smem;               // [2][128][68]

  const int m0 = blockIdx.x * 128;
  const int j0 = blockIdx.y * 64;
  const int n  = blockIdx.z;
  const int t = threadIdx.x;
  const int w = t >> 6, l = t & 63;
  const int pair = w >> 1;       // 0:(z,o) 1:(i,f)
  const int mhalf = w & 1;
  const int g0 = pair ? 1 : 0;   // gate index in WT/bias order z,i,f,o
  const int g1 = pair ? 2 : 3;

  f32x4 acc[4][4][2] = {};

  // A staging: granule t -> (gm=t>>2, kc=t&3); granule t+256 -> gm+64.
  const unsigned aoff1 = (unsigned)(m0 + (t >> 2)) * 2048 + (unsigned)n * 512 + (t & 3) * 8;
  const unsigned aoff2 = aoff1 + 64u * 2048u;
  char* As1d = (char*)As1 + w * 1024;
  char* As2d = (char*)As2 + w * 1024;
  // B staging: wave w stages gate w; granule q*64+l.
  const unsigned bbase = ((unsigned)(w * 4 + n) * 512 + j0 + (l >> 2)) * 1024 + (l & 3) * 8;
  char* Bd = (char*)Bs + w * 4096;

  const int lj = l & 15;
  const int lk = (l >> 4) * 8;

  for (int ks = 0; ks < 32; ++ks) {
    const int kt = ks * 32;
    const bool ph0 = (kt < 512);
    const int kk = kt & 511;
    const __hip_bfloat16* a1 = ph0 ? xb : hb;

    __syncthreads();
    async16(a1 + aoff1 + kk, As1d);
    async16(a1 + aoff2 + kk, As1d + 4096);
    if (ph0) {
      async16(xcb + aoff1 + kk, As2d);
      async16(xcb + aoff2 + kk, As2d + 4096);
    }
#pragma unroll
    for (int q = 0; q < 4; ++q)
      async16(WT + bbase + (unsigned)q * 16u * 1024u + kt, Bd + q * 1024);
    __syncthreads();

    const __hip_bfloat16* Ab = (ph0 ? (pair ? As2 : As1) : As1) + mhalf * 64 * 32;
    bf16x8 af[4];
#pragma unroll
    for (int s = 0; s < 4; ++s)
      af[s] = *(const bf16x8*)(Ab + (s * 16 + lj) * 32 + lk);
#pragma unroll
    for (int sj = 0; sj < 4; ++sj) {
      bf16x8 b0 = *(const bf16x8*)(Bs + g0 * 2048 + (sj * 16 + lj) * 32 + lk);
      bf16x8 b1 = *(const bf16x8*)(Bs + g1 * 2048 + (sj * 16 + lj) * 32 + lk);
#pragma unroll
      for (int s = 0; s < 4; ++s) {
        acc[s][sj][0] = __builtin_amdgcn_mfma_f32_16x16x32_bf16(af[s], b0, acc[s][sj][0], 0, 0, 0);
        acc[s][sj][1] = __builtin_amdgcn_mfma_f32_16x16x32_bf16(af[s], b1, acc[s][sj][1], 0, 0, 0);
      }
    }
  }

  // ---- Epilogue. C/D 16x16 layout: col=lane&15, row=(lane>>4)*4+reg.
  const int r0 = (l >> 4) * 4;
  const int colbase = n * 512 + j0;
  __syncthreads();
  if (pair == 0) {
    // Apply bias + activation for z,o; write bf16 to exchange buffer.
#pragma unroll
    for (int sj = 0; sj < 4; ++sj) {
      const int jc = sj * 16 + lj;
      const float bz_ = bias[0 * 2048 + colbase + jc];
      const float bo_ = bias[3 * 2048 + colbase + jc];
#pragma unroll
      for (int s = 0; s < 4; ++s) {
#pragma unroll
        for (int r = 0; r < 4; ++r) {
          const int lm = mhalf * 64 + s * 16 + r0 + r;
          zo[(0 * 128 + lm) * 68 + jc] = __float2bfloat16(tanhf(acc[s][sj][0][r] + bz_));
          zo[(1 * 128 + lm) * 68 + jc] = __float2bfloat16(sigmoidf_(acc[s][sj][1][r] + bo_));
        }
      }
    }
  }
  __syncthreads();
  if (pair == 1) {
    const size_t HC = (size_t)BB * HH;
#pragma unroll
    for (int sj = 0; sj < 4; ++sj) {
      const int jc = sj * 16 + lj;
      const int col = colbase + jc;
      const float bi_ = bias[1 * 2048 + col];
      const float bf_ = bias[2 * 2048 + col];
#pragma unroll
      for (int s = 0; s < 4; ++s) {
#pragma unroll
        for (int r = 0; r < 4; ++r) {
          const int lm = mhalf * 64 + s * 16 + r0 + r;
          const int row = m0 + lm;
          const float z  = __bfloat162float(zo[(0 * 128 + lm) * 68 + jc]);
          const float og = __bfloat162float(zo[(1 * 128 + lm) * 68 + jc]);
          const float ig = sigmoidf_(acc[s][sj][0][r] + bi_);
          const float fg = sigmoidf_(acc[s][sj][1][r] + bf_);
          const float cp = c_prev[(size_t)row * 2048 + col];
          const float c = fg * cp + ig * z;
          const float hv = og * tanhf(c);
          out[(size_t)row * 2048 + col] = hv;
          out[HC + (size_t)row * 2048 + col] = c;
        }
      }
    }
  }
}

// ---------------------------------------------------------------------------
extern "C" void kernel_launch(void* const* d_in, const int* in_sizes, int n_in,
                              void* d_out, int out_size, void* d_ws, size_t ws_size,
                              hipStream_t stream) {
  const float* x      = (const float*)d_in[0];
  const float* h_prev = (const float*)d_in[1];
  const float* c_prev = (const float*)d_in[2];
  const float* ln_g   = (const float*)d_in[3];
  const float* ln_b   = (const float*)d_in[4];
  const float* conv_w = (const float*)d_in[5];
  const float* conv_b = (const float*)d_in[6];
  const float* Wz = (const float*)d_in[7];
  const float* bz = (const float*)d_in[8];
  const float* Wi = (const float*)d_in[9];
  const float* bi = (const float*)d_in[10];
  const float* Wf = (const float*)d_in[11];
  const float* bf = (const float*)d_in[12];
  const float* Wo = (const float*)d_in[13];
  const float* bo = (const float*)d_in[14];
  const float* Rz = (const float*)d_in[15];
  const float* rbz = (const float*)d_in[16];
  const float* Ri = (const float*)d_in[17];
  const float* rbi = (const float*)d_in[18];
  const float* Rf = (const float*)d_in[19];
  const float* rbf = (const float*)d_in[20];
  const float* Ro = (const float*)d_in[21];
  const float* rbo = (const float*)d_in[22];
  float* out = (float*)d_out;

  char* ws = (char*)d_ws;
  const size_t SZ = (size_t)BB * DD * sizeof(__hip_bfloat16);  // 16 MiB
  __hip_bfloat16* xb  = (__hip_bfloat16*)(ws);
  __hip_bfloat16* xcb = (__hip_bfloat16*)(ws + SZ);
  __hip_bfloat16* hb  = (__hip_bfloat16*)(ws + 2 * SZ);
  __hip_bfloat16* WT  = (__hip_bfloat16*)(ws + 3 * SZ);   // 16 MiB
  float* bias         = (float*)(ws + 4 * SZ);            // 32 KiB

  prep_bias<<<8, 256, 0, stream>>>(bz, bi, bf, bo, rbz, rbi, rbf, rbo, bias);
  prep_w<<<dim3(16, 32, 16), dim3(32, 8), 0, stream>>>(Wz, Wi, Wf, Wo, Rz, Ri, Rf, Ro, WT);
  prep_act<<<BB, 256, 0, stream>>>(x, h_prev, ln_g, ln_b, conv_w, conv_b, xb, xcb, hb);
  gemm_fused<<<dim3(BB / 128, 512 / 64, 4), 256, 0, stream>>>(xb, xcb, hb, WT, bias, c_prev, out);
}

// Round 3
// 355.733 us; speedup vs baseline: 1.4008x; 1.4008x over previous
//
#include <hip/hip_runtime.h>
#include <hip/hip_bf16.h>
#include <math.h>

// Problem constants
#define BB 4096
#define DD 2048
#define HH 2048

typedef __bf16 bf16x8 __attribute__((ext_vector_type(8)));
typedef float f32x4 __attribute__((ext_vector_type(4)));

__device__ __forceinline__ void async16(const void* g, void* l) {
  __builtin_amdgcn_global_load_lds(
      (const __attribute__((address_space(1))) unsigned int*)g,
      (__attribute__((address_space(3))) unsigned int*)l,
      16, 0, 0);
}

__device__ __forceinline__ float sigmoidf_(float x) {
  return 1.0f / (1.0f + __expf(-x));
}

__device__ __forceinline__ void store_bf8(__hip_bfloat16* dst, const float* v) {
  union { __hip_bfloat16 b[8]; uint4 u; } p;
#pragma unroll
  for (int e = 0; e < 8; e++) p.b[e] = __float2bfloat16(v[e]);
  *(uint4*)dst = p.u;
}

// ---------------------------------------------------------------------------
// bias[g][c] = b_g[c] + rb_g[c],  g in {z,i,f,o}
__global__ void prep_bias(const float* __restrict__ bz, const float* __restrict__ bi,
                          const float* __restrict__ bf, const float* __restrict__ bo,
                          const float* __restrict__ rbz, const float* __restrict__ rbi,
                          const float* __restrict__ rbf, const float* __restrict__ rbo,
                          float* __restrict__ bias) {
  int i = blockIdx.x * 256 + threadIdx.x;
  if (i < 2048) {
    bias[0 * 2048 + i] = bz[i] + rbz[i];
    bias[1 * 2048 + i] = bi[i] + rbi[i];
    bias[2 * 2048 + i] = bf[i] + rbf[i];
    bias[3 * 2048 + i] = bo[i] + rbo[i];
  }
}

// ---------------------------------------------------------------------------
// WT2: tiled+swizzled B layout, 16B granules in exact gemm staging order.
// granule index = ((gn*16 + jt)*32 + ks)*128 + j*4 + pc, pc = c ^ ((j>>1)&3),
// holding W/R[n][kt*32 + c*8 .. +8][j0+j] as bf16x8 (k-contiguous).
__global__ __launch_bounds__(256) void prep_w(
    const float* __restrict__ Wz, const float* __restrict__ Wi,
    const float* __restrict__ Wf, const float* __restrict__ Wo,
    const float* __restrict__ Rz, const float* __restrict__ Ri,
    const float* __restrict__ Rf, const float* __restrict__ Ro,
    __hip_bfloat16* __restrict__ WT2) {
  const int jt = blockIdx.x;    // 16 j-tiles of 32
  const int ksg = blockIdx.y;   // 8 groups of 128 k
  const int gn = blockIdx.z;    // g*4 + n
  const int g = gn >> 2, nn = gn & 3;
  const int kg0 = ksg * 128;
  const float* src;
  int krow;
  if (kg0 < 512) { src = (g == 0 ? Wz : g == 1 ? Wi : g == 2 ? Wf : Wo); krow = kg0; }
  else           { src = (g == 0 ? Rz : g == 1 ? Ri : g == 2 ? Rf : Ro); krow = kg0 - 512; }
  const int j0 = jt * 32;
  __shared__ float tile[128][33];
  const int t = threadIdx.x;
  const int jj = t & 31, kk0 = (t >> 5) * 16;
  const float* s0 = src + ((size_t)nn * 512 + krow + kk0) * 512 + j0 + jj;
#pragma unroll
  for (int rr = 0; rr < 16; rr++) tile[kk0 + rr][jj] = s0[(size_t)rr * 512];
  __syncthreads();
#pragma unroll
  for (int q = 0; q < 2; q++) {
    int u = t + q * 256;
    int ksl = u >> 7, j = (u >> 2) & 31, pc = u & 3;
    int c = pc ^ ((j >> 1) & 3);
    float v[8];
#pragma unroll
    for (int e = 0; e < 8; e++) v[e] = tile[ksl * 32 + c * 8 + e][j];
    size_t gr = ((size_t)(gn * 16 + jt) * 32 + ksg * 4 + ksl) * 128 + j * 4 + pc;
    store_bf8(WT2 + gr * 8, v);
  }
}

// ---------------------------------------------------------------------------
// Per row: LN -> conv3 -> SiLU. Emits tiled+swizzled bf16:
//  xh2 granule ((mb*4+n)*32 + ks)*512 + rl*4 + pc : ks<16 = x, ks>=16 = h
//  xc2 granule ((mb*4+n)*16 + ks)*512 + rl*4 + pc : SiLU(conv(LN(x)))
// pc = (t&3) ^ ((rl>>1)&3). Conv neighbors via shfl (no big LDS array).
__global__ __launch_bounds__(256) void prep_act(
    const float* __restrict__ x, const float* __restrict__ h,
    const float* __restrict__ lg, const float* __restrict__ lb,
    const float* __restrict__ cw, const float* __restrict__ cb,
    __hip_bfloat16* __restrict__ xh2, __hip_bfloat16* __restrict__ xc2) {
  const int r = blockIdx.x, t = threadIdx.x, l = t & 63;
  const int mb = r >> 7, rl = r & 127, swz = (rl >> 1) & 3;
  const int n = t >> 6, ktl = (t >> 2) & 15, pc = (t & 3) ^ swz;
  __shared__ float red[8];
  __shared__ float edge[256][2];
  const float* xr = x + (size_t)r * 2048;
  const float* hr = h + (size_t)r * 2048;
  float4 v0 = ((const float4*)xr)[t * 2];
  float4 v1 = ((const float4*)xr)[t * 2 + 1];
  float vv[8] = {v0.x, v0.y, v0.z, v0.w, v1.x, v1.y, v1.z, v1.w};
  float s = 0.f, s2 = 0.f;
#pragma unroll
  for (int e = 0; e < 8; e++) { s += vv[e]; s2 += vv[e] * vv[e]; }
#pragma unroll
  for (int off = 32; off > 0; off >>= 1) {
    s += __shfl_down(s, off);
    s2 += __shfl_down(s2, off);
  }
  const int w = t >> 6;
  if (l == 0) { red[w] = s; red[4 + w] = s2; }
  __syncthreads();
  const float mu = (red[0] + red[1] + red[2] + red[3]) * (1.0f / 2048.0f);
  const float var = (red[4] + red[5] + red[6] + red[7]) * (1.0f / 2048.0f) - mu * mu;
  const float rs = rsqrtf(var + 1e-5f);

  float4 h0 = ((const float4*)hr)[t * 2];
  float4 h1 = ((const float4*)hr)[t * 2 + 1];
  float hh[8] = {h0.x, h0.y, h0.z, h0.w, h1.x, h1.y, h1.z, h1.w};
  float4 g0 = ((const float4*)lg)[t * 2], g1 = ((const float4*)lg)[t * 2 + 1];
  float4 b0 = ((const float4*)lb)[t * 2], b1 = ((const float4*)lb)[t * 2 + 1];
  float gg[8] = {g0.x, g0.y, g0.z, g0.w, g1.x, g1.y, g1.z, g1.w};
  float bb[8] = {b0.x, b0.y, b0.z, b0.w, b1.x, b1.y, b1.z, b1.w};
  float fr[8];
#pragma unroll
  for (int e = 0; e < 8; e++) fr[e] = (vv[e] - mu) * rs * gg[e] + bb[e];

  const size_t bx = ((size_t)(mb * 4 + n) * 32 + ktl) * 512 + rl * 4 + pc;
  const size_t bh = ((size_t)(mb * 4 + n) * 32 + 16 + ktl) * 512 + rl * 4 + pc;
  store_bf8(xh2 + bx * 8, vv);
  store_bf8(xh2 + bh * 8, hh);

  edge[t][0] = fr[6]; edge[t][1] = fr[7];
  __syncthreads();
  float p6 = __shfl_up(fr[6], 1);
  float p7 = __shfl_up(fr[7], 1);
  if (l == 0) {
    p6 = (t > 0) ? edge[t - 1][0] : 0.f;
    p7 = (t > 0) ? edge[t - 1][1] : 0.f;
  }
  const float w0 = cw[0], w1 = cw[1], w2 = cw[2], cbv = cb[0];
  float sc[8];
  {
    float xc0 = w0 * p6 + w1 * p7 + w2 * fr[0] + cbv;
    float xc1 = w0 * p7 + w1 * fr[0] + w2 * fr[1] + cbv;
    sc[0] = xc0 * sigmoidf_(xc0);
    sc[1] = xc1 * sigmoidf_(xc1);
  }
#pragma unroll
  for (int e = 2; e < 8; e++) {
    float xc = w0 * fr[e - 2] + w1 * fr[e - 1] + w2 * fr[e] + cbv;
    sc[e] = xc * sigmoidf_(xc);
  }
  const size_t bc = ((size_t)(mb * 4 + n) * 16 + ktl) * 512 + rl * 4 + pc;
  store_bf8(xc2 + bc * 8, sc);
}

// ---------------------------------------------------------------------------
// Fused 4-gate block GEMM + sLSTM epilogue.
// Grid (32 mb, 16 jt, 4 n), 256 threads = 4 waves (pair = w>>1, mhalf = w&1).
// Wave: 64m x 32j x 2 gates; acc = 4x2x2 f32x4 = 64 VGPR.
// Per k32 iter: 8 ds_read_b128 -> 16 mfma_16x16x32; staging = linear async16
// from pre-tiled xh2/xc2/WT2 (swizzle pc = c ^ ((row>>1)&3) folded into the
// producers, so frag reads are bank-uniform and staging src is ptr + t*16).
__global__ __launch_bounds__(256, 4) void gemm_fused(
    const __hip_bfloat16* __restrict__ xh2, const __hip_bfloat16* __restrict__ xc2,
    const __hip_bfloat16* __restrict__ WT2, const float* __restrict__ bias,
    const float* __restrict__ c_prev, float* __restrict__ out) {
  __shared__ __attribute__((aligned(16))) char smem[24576];
  __hip_bfloat16* As1 = (__hip_bfloat16*)smem;             // [128][32] swz, 8KB
  __hip_bfloat16* As2 = (__hip_bfloat16*)(smem + 8192);    // [128][32] swz, 8KB
  __hip_bfloat16* Bs  = (__hip_bfloat16*)(smem + 16384);   // [4][32][32] swz, 8KB
  __hip_bfloat16* zo  = (__hip_bfloat16*)smem;             // [2][128][36] union

  const int mb = blockIdx.x, jt = blockIdx.y, n = blockIdx.z;
  const int t = threadIdx.x, w = t >> 6, l = t & 63;
  const int pair = w >> 1, mhalf = w & 1;
  const int lj = l & 15;

  // staging sources (running pointers, byte math)
  const char* pA = (const char*)xh2 + (size_t)(mb * 4 + n) * 262144 + t * 16;
  const char* pC = (const char*)xc2 + (size_t)(mb * 4 + n) * 131072 + t * 16;
  const int gate1 = t >> 7;
  const char* pB1 = (const char*)WT2 + (size_t)((gate1 * 4 + n) * 16 + jt) * 65536 + (t & 127) * 16;
  const char* pB2 = (const char*)WT2 + (size_t)(((gate1 + 2) * 4 + n) * 16 + jt) * 65536 + (t & 127) * 16;
  char* dA1 = (char*)As1 + t * 16;
  char* dC1 = (char*)As2 + t * 16;
  char* dB1 = (char*)Bs + t * 16;

  // frag byte offset (swizzled): row*64 + ((c ^ ((row>>1)&3))*16), row ≡ lj mod 16
  const int fo = lj * 64 + (((l >> 4) ^ ((lj >> 1) & 3)) * 16);
  const int g0 = pair ? 1 : 0, g1 = pair ? 2 : 3;

  f32x4 acc[4][2][2] = {};

  for (int ks = 0; ks < 32; ++ks) {
    __syncthreads();
    async16(pA, dA1);
    async16(pA + 4096, dA1 + 4096);
    if (ks < 16) {
      async16(pC, dC1);
      async16(pC + 4096, dC1 + 4096);
    }
    async16(pB1, dB1);
    async16(pB2, dB1 + 4096);
    pA += 8192; pC += 8192; pB1 += 2048; pB2 += 2048;
    __syncthreads();

    const char* Ab = (pair == 1 && ks < 16) ? (const char*)As2 : (const char*)As1;
    Ab += mhalf * 4096 + fo;
    bf16x8 af[4];
#pragma unroll
    for (int s = 0; s < 4; ++s) af[s] = *(const bf16x8*)(Ab + s * 1024);
    const char* Bb = (const char*)Bs + fo;
#pragma unroll
    for (int sj = 0; sj < 2; ++sj) {
      bf16x8 b0 = *(const bf16x8*)(Bb + g0 * 2048 + sj * 1024);
      bf16x8 b1 = *(const bf16x8*)(Bb + g1 * 2048 + sj * 1024);
#pragma unroll
      for (int s = 0; s < 4; ++s) {
        acc[s][sj][0] = __builtin_amdgcn_mfma_f32_16x16x32_bf16(af[s], b0, acc[s][sj][0], 0, 0, 0);
        acc[s][sj][1] = __builtin_amdgcn_mfma_f32_16x16x32_bf16(af[s], b1, acc[s][sj][1], 0, 0, 0);
      }
    }
  }

  // ---- Epilogue. C/D 16x16: col = lane&15, row = (lane>>4)*4 + reg.
  const int r0 = (l >> 4) * 4;
  const int colb = n * 512 + jt * 32;
  __syncthreads();
  if (pair == 0) {
#pragma unroll
    for (int sj = 0; sj < 2; ++sj) {
      const int jc = sj * 16 + lj;
      const float bz_ = bias[colb + jc];
      const float bo_ = bias[3 * 2048 + colb + jc];
#pragma unroll
      for (int s = 0; s < 4; ++s) {
#pragma unroll
        for (int rr = 0; rr < 4; ++rr) {
          const int rl = mhalf * 64 + s * 16 + r0 + rr;
          zo[rl * 36 + jc] = __float2bfloat16(tanhf(acc[s][sj][0][rr] + bz_));
          zo[(128 + rl) * 36 + jc] = __float2bfloat16(sigmoidf_(acc[s][sj][1][rr] + bo_));
        }
      }
    }
  }
  __syncthreads();
  if (pair == 1) {
    const size_t HC = (size_t)BB * HH;
#pragma unroll
    for (int sj = 0; sj < 2; ++sj) {
      const int jc = sj * 16 + lj;
      const int col = colb + jc;
      const float bi_ = bias[1 * 2048 + col];
      const float bf_ = bias[2 * 2048 + col];
#pragma unroll
      for (int s = 0; s < 4; ++s) {
#pragma unroll
        for (int rr = 0; rr < 4; ++rr) {
          const int rl = mhalf * 64 + s * 16 + r0 + rr;
          const int row = mb * 128 + rl;
          const float z  = __bfloat162float(zo[rl * 36 + jc]);
          const float og = __bfloat162float(zo[(128 + rl) * 36 + jc]);
          const float ig = sigmoidf_(acc[s][sj][0][rr] + bi_);
          const float fg = sigmoidf_(acc[s][sj][1][rr] + bf_);
          const float cp = c_prev[(size_t)row * 2048 + col];
          const float c = fg * cp + ig * z;
          const float hv = og * tanhf(c);
          out[(size_t)row * 2048 + col] = hv;
          out[HC + (size_t)row * 2048 + col] = c;
        }
      }
    }
  }
}

// ---------------------------------------------------------------------------
extern "C" void kernel_launch(void* const* d_in, const int* in_sizes, int n_in,
                              void* d_out, int out_size, void* d_ws, size_t ws_size,
                              hipStream_t stream) {
  const float* x      = (const float*)d_in[0];
  const float* h_prev = (const float*)d_in[1];
  const float* c_prev = (const float*)d_in[2];
  const float* ln_g   = (const float*)d_in[3];
  const float* ln_b   = (const float*)d_in[4];
  const float* conv_w = (const float*)d_in[5];
  const float* conv_b = (const float*)d_in[6];
  const float* Wz = (const float*)d_in[7];
  const float* bz = (const float*)d_in[8];
  const float* Wi = (const float*)d_in[9];
  const float* bi = (const float*)d_in[10];
  const float* Wf = (const float*)d_in[11];
  const float* bf = (const float*)d_in[12];
  const float* Wo = (const float*)d_in[13];
  const float* bo = (const float*)d_in[14];
  const float* Rz = (const float*)d_in[15];
  const float* rbz = (const float*)d_in[16];
  const float* Ri = (const float*)d_in[17];
  const float* rbi = (const float*)d_in[18];
  const float* Rf = (const float*)d_in[19];
  const float* rbf = (const float*)d_in[20];
  const float* Ro = (const float*)d_in[21];
  const float* rbo = (const float*)d_in[22];
  float* out = (float*)d_out;

  char* ws = (char*)d_ws;
  __hip_bfloat16* xh2 = (__hip_bfloat16*)(ws);                       // 32 MiB
  __hip_bfloat16* xc2 = (__hip_bfloat16*)(ws + 33554432);            // 16 MiB
  __hip_bfloat16* WT2 = (__hip_bfloat16*)(ws + 33554432 + 16777216); // 16 MiB
  float* bias         = (float*)(ws + 33554432 + 2 * 16777216);      // 32 KiB

  prep_bias<<<8, 256, 0, stream>>>(bz, bi, bf, bo, rbz, rbi, rbf, rbo, bias);
  prep_w<<<dim3(16, 8, 16), 256, 0, stream>>>(Wz, Wi, Wf, Wo, Rz, Ri, Rf, Ro, WT2);
  prep_act<<<BB, 256, 0, stream>>>(x, h_prev, ln_g, ln_b, conv_w, conv_b, xh2, xc2);
  gemm_fused<<<dim3(32, 16, 4), 256, 0, stream>>>(xh2, xc2, WT2, bias, c_prev, out);
}

// Round 4
// 334.214 us; speedup vs baseline: 1.4910x; 1.0644x over previous
//
#include <hip/hip_runtime.h>
#include <hip/hip_bf16.h>
#include <math.h>

// Problem constants
#define BB 4096
#define DD 2048
#define HH 2048

typedef __bf16 bf16x8 __attribute__((ext_vector_type(8)));
typedef float f32x4 __attribute__((ext_vector_type(4)));

__device__ __forceinline__ void async16(const void* g, void* l) {
  __builtin_amdgcn_global_load_lds(
      (const __attribute__((address_space(1))) unsigned int*)g,
      (__attribute__((address_space(3))) unsigned int*)l,
      16, 0, 0);
}

__device__ __forceinline__ float sigmoidf_(float x) {
  return 1.0f / (1.0f + __expf(-x));
}
__device__ __forceinline__ float tanhf_(float x) {
  float t = __expf(-2.0f * fabsf(x));
  return copysignf((1.0f - t) / (1.0f + t), x);
}

__device__ __forceinline__ void store_bf8(__hip_bfloat16* dst, const float* v) {
  union { __hip_bfloat16 b[8]; uint4 u; } p;
#pragma unroll
  for (int e = 0; e < 8; e++) p.b[e] = __float2bfloat16(v[e]);
  *(uint4*)dst = p.u;
}

// ---------------------------------------------------------------------------
// bias[g][c] = b_g[c] + rb_g[c],  g in {z,i,f,o}
__global__ void prep_bias(const float* __restrict__ bz, const float* __restrict__ bi,
                          const float* __restrict__ bf, const float* __restrict__ bo,
                          const float* __restrict__ rbz, const float* __restrict__ rbi,
                          const float* __restrict__ rbf, const float* __restrict__ rbo,
                          float* __restrict__ bias) {
  int i = blockIdx.x * 256 + threadIdx.x;
  if (i < 2048) {
    bias[0 * 2048 + i] = bz[i] + rbz[i];
    bias[1 * 2048 + i] = bi[i] + rbi[i];
    bias[2 * 2048 + i] = bf[i] + rbf[i];
    bias[3 * 2048 + i] = bo[i] + rbo[i];
  }
}

// ---------------------------------------------------------------------------
// WT2 granule ((gn*16 + jt)*32 + ks)*128 + j*4 + pc  (16B granules), holding
// W/R[n][ks*32 + c*8 .. +8][jt*32+j] bf16x8, c = pc ^ ((j>>1)&3).
// Direct global gather (no LDS): per e-step a wave reads 4 rows x 64B.
__global__ __launch_bounds__(256) void prep_w(
    const float* __restrict__ Wz, const float* __restrict__ Wi,
    const float* __restrict__ Wf, const float* __restrict__ Wo,
    const float* __restrict__ Rz, const float* __restrict__ Ri,
    const float* __restrict__ Rf, const float* __restrict__ Ro,
    __hip_bfloat16* __restrict__ WT2) {
  const int jt = blockIdx.x;    // 16 j-tiles of 32
  const int ksg = blockIdx.y;   // 8 groups of 128 k
  const int gn = blockIdx.z;    // g*4 + n
  const int g = gn >> 2, nn = gn & 3;
  const float* src;
  if (ksg < 4) src = (g == 0 ? Wz : g == 1 ? Wi : g == 2 ? Wf : Wo);
  else         src = (g == 0 ? Rz : g == 1 ? Ri : g == 2 ? Rf : Ro);
  const int t = threadIdx.x;
#pragma unroll
  for (int q = 0; q < 2; q++) {
    int u = t + q * 256;
    int ksl = u >> 7, j = (u >> 2) & 31, pc = u & 3;
    int c = pc ^ ((j >> 1) & 3);
    int kr = (ksg & 3) * 128 + ksl * 32 + c * 8;
    const float* s0 = src + ((size_t)nn * 512 + kr) * 512 + jt * 32 + j;
    float v[8];
#pragma unroll
    for (int e = 0; e < 8; e++) v[e] = s0[(size_t)e * 512];
    size_t gr = ((size_t)(gn * 16 + jt) * 32 + ksg * 4 + ksl) * 128 + j * 4 + pc;
    store_bf8(WT2 + gr * 8, v);
  }
}

// ---------------------------------------------------------------------------
// Per row: LN -> conv3 -> SiLU. Emits tiled+swizzled bf16:
//  xh2 granule ((mb*4+n)*32 + ks)*512 + rl*4 + pc : ks<16 = x, ks>=16 = h
//  xc2 granule ((mb*4+n)*16 + ks)*512 + rl*4 + pc : SiLU(conv(LN(x)))
__global__ __launch_bounds__(256) void prep_act(
    const float* __restrict__ x, const float* __restrict__ h,
    const float* __restrict__ lg, const float* __restrict__ lb,
    const float* __restrict__ cw, const float* __restrict__ cb,
    __hip_bfloat16* __restrict__ xh2, __hip_bfloat16* __restrict__ xc2) {
  const int r = blockIdx.x, t = threadIdx.x, l = t & 63;
  const int mb = r >> 7, rl = r & 127, swz = (rl >> 1) & 3;
  const int n = t >> 6, ktl = (t >> 2) & 15, pc = (t & 3) ^ swz;
  __shared__ float red[8];
  __shared__ float edge[256][2];
  const float* xr = x + (size_t)r * 2048;
  const float* hr = h + (size_t)r * 2048;
  float4 v0 = ((const float4*)xr)[t * 2];
  float4 v1 = ((const float4*)xr)[t * 2 + 1];
  float vv[8] = {v0.x, v0.y, v0.z, v0.w, v1.x, v1.y, v1.z, v1.w};
  float s = 0.f, s2 = 0.f;
#pragma unroll
  for (int e = 0; e < 8; e++) { s += vv[e]; s2 += vv[e] * vv[e]; }
#pragma unroll
  for (int off = 32; off > 0; off >>= 1) {
    s += __shfl_down(s, off);
    s2 += __shfl_down(s2, off);
  }
  const int w = t >> 6;
  if (l == 0) { red[w] = s; red[4 + w] = s2; }
  __syncthreads();
  const float mu = (red[0] + red[1] + red[2] + red[3]) * (1.0f / 2048.0f);
  const float var = (red[4] + red[5] + red[6] + red[7]) * (1.0f / 2048.0f) - mu * mu;
  const float rs = rsqrtf(var + 1e-5f);

  float4 h0 = ((const float4*)hr)[t * 2];
  float4 h1 = ((const float4*)hr)[t * 2 + 1];
  float hh[8] = {h0.x, h0.y, h0.z, h0.w, h1.x, h1.y, h1.z, h1.w};
  float4 g0 = ((const float4*)lg)[t * 2], g1 = ((const float4*)lg)[t * 2 + 1];
  float4 b0 = ((const float4*)lb)[t * 2], b1 = ((const float4*)lb)[t * 2 + 1];
  float gg[8] = {g0.x, g0.y, g0.z, g0.w, g1.x, g1.y, g1.z, g1.w};
  float bb[8] = {b0.x, b0.y, b0.z, b0.w, b1.x, b1.y, b1.z, b1.w};
  float fr[8];
#pragma unroll
  for (int e = 0; e < 8; e++) fr[e] = (vv[e] - mu) * rs * gg[e] + bb[e];

  const size_t bx = ((size_t)(mb * 4 + n) * 32 + ktl) * 512 + rl * 4 + pc;
  const size_t bh = ((size_t)(mb * 4 + n) * 32 + 16 + ktl) * 512 + rl * 4 + pc;
  store_bf8(xh2 + bx * 8, vv);
  store_bf8(xh2 + bh * 8, hh);

  edge[t][0] = fr[6]; edge[t][1] = fr[7];
  __syncthreads();
  float p6 = __shfl_up(fr[6], 1);
  float p7 = __shfl_up(fr[7], 1);
  if (l == 0) {
    p6 = (t > 0) ? edge[t - 1][0] : 0.f;
    p7 = (t > 0) ? edge[t - 1][1] : 0.f;
  }
  const float w0 = cw[0], w1 = cw[1], w2 = cw[2], cbv = cb[0];
  float sc[8];
  {
    float xc0 = w0 * p6 + w1 * p7 + w2 * fr[0] + cbv;
    float xc1 = w0 * p7 + w1 * fr[0] + w2 * fr[1] + cbv;
    sc[0] = xc0 * sigmoidf_(xc0);
    sc[1] = xc1 * sigmoidf_(xc1);
  }
#pragma unroll
  for (int e = 2; e < 8; e++) {
    float xc = w0 * fr[e - 2] + w1 * fr[e - 1] + w2 * fr[e] + cbv;
    sc[e] = xc * sigmoidf_(xc);
  }
  const size_t bc = ((size_t)(mb * 4 + n) * 16 + ktl) * 512 + rl * 4 + pc;
  store_bf8(xc2 + bc * 8, sc);
}

// ---------------------------------------------------------------------------
// Fused 4-gate block GEMM + sLSTM epilogue.
// Grid (32 mb, 8 jt, 4 n), 512 threads = 8 waves.
// Wave w: pair = w>>2 (0:(z,o), 1:(i,f)), mhalf = (w>>1)&1, jhalf = w&1.
// Wave tile 64m x 32j x 2 gates, acc = 64 AGPR. BK=64: per iter the block
// stages 64KB (A 16 + C 16 + B 32) and runs 256 MFMA; 16 barrier iters.
// LDS 64KB -> 2 blocks/CU = 16 waves (register cap anyway: 64 VGPR+64 AGPR).
__global__ __launch_bounds__(512, 4) void gemm_fused(
    const __hip_bfloat16* __restrict__ xh2, const __hip_bfloat16* __restrict__ xc2,
    const __hip_bfloat16* __restrict__ WT2, const float* __restrict__ bias,
    const float* __restrict__ c_prev, float* __restrict__ out) {
  // smem map: [0,16K) A=x/h  [2kh][128m][64B swz]
  //           [16K,32K) C=xc [2kh][128m][64B swz]
  //           [32K,64K) B    [4g][2jth][2kh][32j][64B swz]
  // union: zo bf16 [2][128][72] = 36,864B
  __shared__ __attribute__((aligned(16))) char smem[65536];
  __hip_bfloat16* zo = (__hip_bfloat16*)smem;

  const int mb = blockIdx.x, jt = blockIdx.y, n = blockIdx.z;
  const int t = threadIdx.x, w = t >> 6, l = t & 63;
  const int pair = w >> 2, mhalf = (w >> 1) & 1, jhalf = w & 1;
  const int lj = l & 15;

  // staging sources
  const char* pA = (const char*)xh2 + (size_t)(mb * 4 + n) * 262144 + t * 16;
  const char* pC = (const char*)xc2 + (size_t)(mb * 4 + n) * 131072 + t * 16;
  // B: thread t covers (jth=(t>>8)&1, kh=(t>>7)&1, gr=t&127) for each gate g.
  const char* pB = (const char*)WT2 +
      (size_t)(n * 16 + jt * 2 + ((t >> 8) & 1)) * 65536 + ((t >> 7) & 1) * 2048 + (t & 127) * 16;
  char* dA = smem + t * 16;
  char* dB = smem + 32768 + t * 16;

  // frag byte offset (swizzled): row lj -> lj*64 + (chunk ^ ((lj>>1)&3))*16
  const int fo = lj * 64 + (((l >> 4) ^ ((lj >> 1) & 3)) * 16);
  const int g0 = pair ? 1 : 0, g1 = pair ? 2 : 3;

  f32x4 acc[4][2][2] = {};

  for (int ks2 = 0; ks2 < 16; ++ks2) {
    __syncthreads();
    async16(pA, dA);
    async16(pA + 8192, dA + 8192);
    if (ks2 < 8) {
      async16(pC, dA + 16384);
      async16(pC + 8192, dA + 24576);
    }
    async16(pB, dB);
    async16(pB + 4194304, dB + 8192);
    async16(pB + 8388608, dB + 16384);
    async16(pB + 12582912, dB + 24576);
    pA += 16384; pC += 16384; pB += 4096;
    __syncthreads();

    const char* Ab = ((ks2 < 8 && pair) ? smem + 16384 : smem) + mhalf * 4096 + fo;
    const char* Bb = smem + 32768 + jhalf * 4096 + fo;
#pragma unroll
    for (int kh = 0; kh < 2; ++kh) {
      bf16x8 af[4];
#pragma unroll
      for (int s = 0; s < 4; ++s)
        af[s] = *(const bf16x8*)(Ab + kh * 8192 + s * 1024);
#pragma unroll
      for (int sj = 0; sj < 2; ++sj) {
        bf16x8 b0 = *(const bf16x8*)(Bb + g0 * 8192 + kh * 2048 + sj * 1024);
        bf16x8 b1 = *(const bf16x8*)(Bb + g1 * 8192 + kh * 2048 + sj * 1024);
#pragma unroll
        for (int s = 0; s < 4; ++s) {
          acc[s][sj][0] = __builtin_amdgcn_mfma_f32_16x16x32_bf16(af[s], b0, acc[s][sj][0], 0, 0, 0);
          acc[s][sj][1] = __builtin_amdgcn_mfma_f32_16x16x32_bf16(af[s], b1, acc[s][sj][1], 0, 0, 0);
        }
      }
    }
  }

  // ---- Epilogue. C/D 16x16: col = lane&15, row = (lane>>4)*4 + reg.
  const int r0 = (l >> 4) * 4;
  const int colb = n * 512 + jt * 64;
  __syncthreads();
  if (pair == 0) {
#pragma unroll
    for (int sj = 0; sj < 2; ++sj) {
      const int jc = jhalf * 32 + sj * 16 + lj;
      const float bz_ = bias[colb + jc];
      const float bo_ = bias[3 * 2048 + colb + jc];
#pragma unroll
      for (int s = 0; s < 4; ++s) {
#pragma unroll
        for (int rr = 0; rr < 4; ++rr) {
          const int rl = mhalf * 64 + s * 16 + r0 + rr;
          zo[rl * 72 + jc] = __float2bfloat16(tanhf_(acc[s][sj][0][rr] + bz_));
          zo[(128 + rl) * 72 + jc] = __float2bfloat16(sigmoidf_(acc[s][sj][1][rr] + bo_));
        }
      }
    }
  }
  __syncthreads();
  if (pair == 1) {
    const size_t HC = (size_t)BB * HH;
#pragma unroll
    for (int sj = 0; sj < 2; ++sj) {
      const int jc = jhalf * 32 + sj * 16 + lj;
      const int col = colb + jc;
      const float bi_ = bias[1 * 2048 + col];
      const float bf_ = bias[2 * 2048 + col];
#pragma unroll
      for (int s = 0; s < 4; ++s) {
#pragma unroll
        for (int rr = 0; rr < 4; ++rr) {
          const int rl = mhalf * 64 + s * 16 + r0 + rr;
          const int row = mb * 128 + rl;
          const float z  = __bfloat162float(zo[rl * 72 + jc]);
          const float og = __bfloat162float(zo[(128 + rl) * 72 + jc]);
          const float ig = sigmoidf_(acc[s][sj][0][rr] + bi_);
          const float fg = sigmoidf_(acc[s][sj][1][rr] + bf_);
          const float cp = c_prev[(size_t)row * 2048 + col];
          const float c = fg * cp + ig * z;
          const float hv = og * tanhf_(c);
          out[(size_t)row * 2048 + col] = hv;
          out[HC + (size_t)row * 2048 + col] = c;
        }
      }
    }
  }
}

// ---------------------------------------------------------------------------
extern "C" void kernel_launch(void* const* d_in, const int* in_sizes, int n_in,
                              void* d_out, int out_size, void* d_ws, size_t ws_size,
                              hipStream_t stream) {
  const float* x      = (const float*)d_in[0];
  const float* h_prev = (const float*)d_in[1];
  const float* c_prev = (const float*)d_in[2];
  const float* ln_g   = (const float*)d_in[3];
  const float* ln_b   = (const float*)d_in[4];
  const float* conv_w = (const float*)d_in[5];
  const float* conv_b = (const float*)d_in[6];
  const float* Wz = (const float*)d_in[7];
  const float* bz = (const float*)d_in[8];
  const float* Wi = (const float*)d_in[9];
  const float* bi = (const float*)d_in[10];
  const float* Wf = (const float*)d_in[11];
  const float* bf = (const float*)d_in[12];
  const float* Wo = (const float*)d_in[13];
  const float* bo = (const float*)d_in[14];
  const float* Rz = (const float*)d_in[15];
  const float* rbz = (const float*)d_in[16];
  const float* Ri = (const float*)d_in[17];
  const float* rbi = (const float*)d_in[18];
  const float* Rf = (const float*)d_in[19];
  const float* rbf = (const float*)d_in[20];
  const float* Ro = (const float*)d_in[21];
  const float* rbo = (const float*)d_in[22];
  float* out = (float*)d_out;

  char* ws = (char*)d_ws;
  __hip_bfloat16* xh2 = (__hip_bfloat16*)(ws);                       // 32 MiB
  __hip_bfloat16* xc2 = (__hip_bfloat16*)(ws + 33554432);            // 16 MiB
  __hip_bfloat16* WT2 = (__hip_bfloat16*)(ws + 33554432 + 16777216); // 16 MiB
  float* bias         = (float*)(ws + 33554432 + 2 * 16777216);      // 32 KiB

  prep_bias<<<8, 256, 0, stream>>>(bz, bi, bf, bo, rbz, rbi, rbf, rbo, bias);
  prep_w<<<dim3(16, 8, 16), 256, 0, stream>>>(Wz, Wi, Wf, Wo, Rz, Ri, Rf, Ro, WT2);
  prep_act<<<BB, 256, 0, stream>>>(x, h_prev, ln_g, ln_b, conv_w, conv_b, xh2, xc2);
  gemm_fused<<<dim3(32, 8, 4), 512, 0, stream>>>(xh2, xc2, WT2, bias, c_prev, out);
}